// Round 3
// baseline (1646.483 us; speedup 1.0000x reference)
//
#include <hip/hip_runtime.h>

#define NN 100000
#define CC 128
#define KK 27
#define MM 60000
#define NPAIR (KK * MM)            // 1,620,000
#define BBATCH 8
#define CRR 32
#define TM 64
#define NBLK ((MM + TM - 1) / TM)  // 938
#define NSB 98                     // ceil(NN / 1024)

typedef _Float16 half8 __attribute__((ext_vector_type(8)));
typedef float floatx4 __attribute__((ext_vector_type(4)));

struct __align__(8) Half4 { _Float16 x, y, z, w; };

// ---------------- conversion kernels ----------------

__global__ __launch_bounds__(256) void convert_x_kernel(
    const float* __restrict__ x, _Float16* __restrict__ xh) {
    int i = blockIdx.x * 256 + threadIdx.x;
    if (i >= NN * (CC / 4)) return;
    float4 v = ((const float4*)x)[i];
    Half4 o;
    o.x = (_Float16)v.x; o.y = (_Float16)v.y;
    o.z = (_Float16)v.z; o.w = (_Float16)v.w;
    ((Half4*)xh)[i] = o;
}

// Wt[k][co][ci] = W[k][ci][co], f16, via LDS tile transpose (coalesced both sides)
__global__ __launch_bounds__(256) void transpose_w_kernel(
    const float* __restrict__ W, _Float16* __restrict__ Wt) {
    __shared__ float tile[32][33];
    int k = blockIdx.x >> 4;
    int tl = blockIdx.x & 15;
    int tr = (tl >> 2) * 32;       // ci base
    int tc = (tl & 3) * 32;        // co base
    int c = threadIdx.x & 31;
    int r8 = threadIdx.x >> 5;     // 0..7
    const float* Wk = W + (size_t)k * CC * CC;
    _Float16* Wo = Wt + (size_t)k * CC * CC;
    #pragma unroll
    for (int i = 0; i < 4; ++i) {
        int r = r8 + i * 8;
        tile[r][c] = Wk[(tr + r) * CC + tc + c];
    }
    __syncthreads();
    #pragma unroll
    for (int i = 0; i < 4; ++i) {
        int r = r8 + i * 8;
        Wo[(tc + r) * CC + tr + c] = (_Float16)tile[c][r];
    }
}

// ---------------- CSR build (out_idx shared by both convs) ----------------

__global__ __launch_bounds__(256) void hist_kernel(
    const int* __restrict__ oidx, int* __restrict__ counts) {
    int i = blockIdx.x * 256 + threadIdx.x;
    if (i < NPAIR) atomicAdd(&counts[oidx[i]], 1);
}

__global__ __launch_bounds__(256) void scan1_kernel(
    const int* __restrict__ counts, int* __restrict__ offsets, int* __restrict__ bsum) {
    __shared__ int ls[256];
    int b = blockIdx.x, t = threadIdx.x;
    int base = b * 1024 + t * 4;
    int v0 = (base + 0 < NN) ? counts[base + 0] : 0;
    int v1 = (base + 1 < NN) ? counts[base + 1] : 0;
    int v2 = (base + 2 < NN) ? counts[base + 2] : 0;
    int v3 = (base + 3 < NN) ? counts[base + 3] : 0;
    int s = v0 + v1 + v2 + v3;
    ls[t] = s;
    __syncthreads();
    for (int off = 1; off < 256; off <<= 1) {
        int x = (t >= off) ? ls[t - off] : 0;
        __syncthreads();
        if (t >= off) ls[t] += x;
        __syncthreads();
    }
    int ep = ls[t] - s;            // exclusive prefix for this thread
    if (base + 0 < NN) offsets[base + 0] = ep;
    if (base + 1 < NN) offsets[base + 1] = ep + v0;
    if (base + 2 < NN) offsets[base + 2] = ep + v0 + v1;
    if (base + 3 < NN) offsets[base + 3] = ep + v0 + v1 + v2;
    if (t == 255) bsum[b] = ls[255];
}

__global__ void scan2_kernel(const int* __restrict__ bsum, int* __restrict__ bbase) {
    __shared__ int ls[128];
    int t = threadIdx.x;
    int s = (t < NSB) ? bsum[t] : 0;
    ls[t] = s;
    __syncthreads();
    for (int off = 1; off < 128; off <<= 1) {
        int x = (t >= off) ? ls[t - off] : 0;
        __syncthreads();
        if (t >= off) ls[t] += x;
        __syncthreads();
    }
    if (t < NSB) bbase[t] = ls[t] - s;
}

__global__ __launch_bounds__(256) void scan3_kernel(
    int* __restrict__ offsets, const int* __restrict__ bbase) {
    int b = blockIdx.x, t = threadIdx.x;
    int add = bbase[b];
    int base = b * 1024 + t * 4;
    #pragma unroll
    for (int i = 0; i < 4; ++i)
        if (base + i < NN) offsets[base + i] += add;
    if (b == 0 && t == 0) offsets[NN] = NPAIR;
}

// rank[i] = CSR position of pair i (order within a segment irrelevant for the sum)
__global__ __launch_bounds__(256) void fill_kernel(
    const int* __restrict__ oidx, const int* __restrict__ offsets,
    int* __restrict__ counts, int* __restrict__ rank) {
    int i = blockIdx.x * 256 + threadIdx.x;
    if (i < NPAIR) {
        int o = oidx[i];
        int old = atomicSub(&counts[o], 1);
        rank[i] = offsets[o] + old - 1;
    }
}

// ---------------- conv phase 1: gather-MFMA -> y (CSR-permuted rows) ----------------
// y row layout: channel-transposed p = (c&15)*8 + (c>>4), so each lane's 8
// fragment values are one contiguous half8 -> single 16B coalesced store.
__global__ __launch_bounds__(256) void ygemm_kernel(
    const _Float16* __restrict__ xh,     // [NN][CC]
    const _Float16* __restrict__ Wt,     // [KK][co][ci]
    const int* __restrict__ in_idx,      // [KK][MM]
    const int* __restrict__ rank,        // [NPAIR]
    _Float16* __restrict__ y)            // [NPAIR][CC]
{
    __shared__ __align__(16) _Float16 Alds[TM][136];
    __shared__ __align__(16) _Float16 Blds[CC][136];

    int k  = blockIdx.x / NBLK;
    int tb = blockIdx.x % NBLK;
    int m0 = tb * TM;
    int tid = threadIdx.x;

    const _Float16* Wk = Wt + (size_t)k * CC * CC;
    #pragma unroll
    for (int i = 0; i < 8; ++i) {
        int ch = tid + i * 256;
        int r = ch >> 4;
        int c8 = (ch & 15) << 3;
        *(half8*)&Blds[r][c8] = *(const half8*)&Wk[r * CC + c8];
    }
    const int* ii = in_idx + (size_t)k * MM + m0;
    #pragma unroll
    for (int i = 0; i < 4; ++i) {
        int r = (tid >> 4) + i * 16;
        int c8 = (tid & 15) << 3;
        if (m0 + r < MM) {
            int g = ii[r];
            *(half8*)&Alds[r][c8] = *(const half8*)&xh[(size_t)g * CC + c8];
        } else {
            half8 z = {};
            *(half8*)&Alds[r][c8] = z;
        }
    }
    __syncthreads();

    int w = tid >> 6;
    int lane = tid & 63;
    int lr = lane & 15;
    int lk = lane >> 4;

    floatx4 acc[8];
    #pragma unroll
    for (int f = 0; f < 8; ++f) acc[f] = (floatx4){0.f, 0.f, 0.f, 0.f};

    #pragma unroll
    for (int kc = 0; kc < 4; ++kc) {
        half8 a = *(const half8*)&Alds[w * 16 + lr][kc * 32 + lk * 8];
        #pragma unroll
        for (int f = 0; f < 8; ++f) {
            half8 bb = *(const half8*)&Blds[f * 16 + lr][kc * 32 + lk * 8];
            acc[f] = __builtin_amdgcn_mfma_f32_16x16x32_f16(a, bb, acc[f], 0, 0, 0);
        }
    }

    int rbase = w * 16 + lk * 4;
    #pragma unroll
    for (int j = 0; j < 4; ++j) {
        int m = m0 + rbase + j;
        if (m < MM) {
            int pos = rank[(size_t)k * MM + m];   // uniform across the 16-lane group
            half8 hv;
            #pragma unroll
            for (int f = 0; f < 8; ++f) hv[f] = (_Float16)acc[f][j];
            *(half8*)&y[(size_t)pos * CC + lr * 8] = hv;
        }
    }
}

// ---------------- conv phase 2: contiguous segment reduce ----------------
// 16 lanes per output row; segments consecutive in y -> pure streaming read.
__global__ __launch_bounds__(256) void reduce_kernel(
    const _Float16* __restrict__ y, const int* __restrict__ offsets,
    float* __restrict__ out) {
    int t = threadIdx.x;
    int g = t >> 4;
    int l = t & 15;
    int o = blockIdx.x * 16 + g;           // grid 6250*16 == NN exactly
    int s0 = offsets[o], s1 = offsets[o + 1];
    float a[8] = {0.f, 0.f, 0.f, 0.f, 0.f, 0.f, 0.f, 0.f};
    for (int p = s0; p < s1; ++p) {
        half8 v = *(const half8*)&y[(size_t)p * CC + l * 8];
        #pragma unroll
        for (int i = 0; i < 8; ++i) a[i] += (float)v[i];
    }
    float* orow = out + (size_t)o * CC;
    #pragma unroll
    for (int i = 0; i < 8; ++i) orow[i * 16 + l] = a[i];   // p=l*8+i <-> c=i*16+l
}

// ---------------- fallback: original atomic-scatter conv ----------------
__global__ __launch_bounds__(256) void conv_kernel(
    const _Float16* __restrict__ xh, const _Float16* __restrict__ Wt,
    const int* __restrict__ in_idx, const int* __restrict__ out_idx,
    float* __restrict__ out) {
    __shared__ __align__(16) _Float16 Alds[TM][136];
    __shared__ __align__(16) _Float16 Blds[CC][136];
    int k  = blockIdx.x / NBLK;
    int tb = blockIdx.x % NBLK;
    int m0 = tb * TM;
    int tid = threadIdx.x;
    const _Float16* Wk = Wt + (size_t)k * CC * CC;
    #pragma unroll
    for (int i = 0; i < 8; ++i) {
        int ch = tid + i * 256;
        int r = ch >> 4, c8 = (ch & 15) << 3;
        *(half8*)&Blds[r][c8] = *(const half8*)&Wk[r * CC + c8];
    }
    const int* ii = in_idx + (size_t)k * MM + m0;
    #pragma unroll
    for (int i = 0; i < 4; ++i) {
        int r = (tid >> 4) + i * 16, c8 = (tid & 15) << 3;
        if (m0 + r < MM) {
            int g = ii[r];
            *(half8*)&Alds[r][c8] = *(const half8*)&xh[(size_t)g * CC + c8];
        } else { half8 z = {}; *(half8*)&Alds[r][c8] = z; }
    }
    __syncthreads();
    int w = tid >> 6, lane = tid & 63;
    int lr = lane & 15, lk = lane >> 4;
    floatx4 acc[8];
    #pragma unroll
    for (int f = 0; f < 8; ++f) acc[f] = (floatx4){0.f, 0.f, 0.f, 0.f};
    #pragma unroll
    for (int kc = 0; kc < 4; ++kc) {
        half8 a = *(const half8*)&Alds[w * 16 + lr][kc * 32 + lk * 8];
        #pragma unroll
        for (int f = 0; f < 8; ++f) {
            half8 bb = *(const half8*)&Blds[f * 16 + lr][kc * 32 + lk * 8];
            acc[f] = __builtin_amdgcn_mfma_f32_16x16x32_f16(a, bb, acc[f], 0, 0, 0);
        }
    }
    const int* oi = out_idx + (size_t)k * MM + m0;
    int mb = w * 16 + lk * 4;
    #pragma unroll
    for (int j = 0; j < 4; ++j) {
        int m = m0 + mb + j;
        if (m < MM) {
            int o = oi[mb + j];
            float* orow = out + (size_t)o * CC + lr;
            #pragma unroll
            for (int f = 0; f < 8; ++f)
                atomicAdd(orow + f * 16, acc[f][j]);
        }
    }
}

// ---------------- batchnorm / SE / epilogue (unchanged math) ----------------

__global__ __launch_bounds__(256) void bn_stats_kernel(
    const float* __restrict__ in, float* __restrict__ stats, int nrows, int rpb) {
    int c = threadIdx.x & 127;
    int p = threadIdx.x >> 7;
    int r0 = blockIdx.x * rpb;
    int r1 = min(nrows, r0 + rpb);
    float s = 0.f, s2 = 0.f;
    for (int r = r0 + p; r < r1; r += 2) {
        float v = in[(size_t)r * CC + c];
        s += v; s2 += v * v;
    }
    __shared__ float ls[256], ls2[256];
    ls[threadIdx.x] = s; ls2[threadIdx.x] = s2;
    __syncthreads();
    if (p == 0) {
        atomicAdd(&stats[c],      ls[c] + ls[c + 128]);
        atomicAdd(&stats[CC + c], ls2[c] + ls2[c + 128]);
    }
}

__global__ void bn_finalize_kernel(
    const float* __restrict__ stats, const float* __restrict__ gamma,
    const float* __restrict__ beta, float* __restrict__ ss) {
    int c = threadIdx.x;
    if (c < CC) {
        float mean = stats[c] * (1.f / NN);
        float var = stats[CC + c] * (1.f / NN) - mean * mean;
        float sc = gamma[c] * rsqrtf(var + 1e-5f);
        ss[c] = sc;
        ss[CC + c] = beta[c] - mean * sc;
    }
}

__global__ __launch_bounds__(256) void pool_kernel(
    const float* __restrict__ in, const float* __restrict__ ss,
    const int* __restrict__ batch_id, float* __restrict__ pooled,
    int nrows, int rpb) {
    int c = threadIdx.x & 127;
    int p = threadIdx.x >> 7;
    float sc = ss[c], sh = ss[CC + c];
    int r0 = blockIdx.x * rpb;
    int r1 = min(nrows, r0 + rpb);
    float acc = 0.f; int cur = -1;
    for (int r = r0 + p; r < r1; r += 2) {
        int b = batch_id[r];
        float v = fmaxf(fmaf(in[(size_t)r * CC + c], sc, sh), 0.f);
        if (b != cur) {
            if (cur >= 0) atomicAdd(&pooled[cur * CC + c], acc);
            cur = b; acc = 0.f;
        }
        acc += v;
    }
    if (cur >= 0) atomicAdd(&pooled[cur * CC + c], acc);
}

__global__ __launch_bounds__(256) void se_kernel(
    const float* __restrict__ pooled, const float* __restrict__ fc1,
    const float* __restrict__ fc2, float* __restrict__ se) {
    __shared__ float h[BBATCH][CRR];
    int tid = threadIdx.x;
    {
        int b = tid >> 5, j = tid & 31;
        float a = 0.f;
        for (int c = 0; c < CC; ++c) a += pooled[b * CC + c] * fc1[c * CRR + j];
        h[b][j] = fmaxf(a, 0.f);
    }
    __syncthreads();
    #pragma unroll
    for (int i = 0; i < 4; ++i) {
        int idx = tid + i * 256;
        int b = idx >> 7, c = idx & 127;
        float a = 0.f;
        #pragma unroll
        for (int j = 0; j < CRR; ++j) a += h[b][j] * fc2[j * CC + c];
        se[b * CC + c] = 1.f / (1.f + expf(-a));
    }
}

__global__ __launch_bounds__(256) void scale_convert_kernel(
    const float* __restrict__ in, const float* __restrict__ ss,
    const float* __restrict__ se, const int* __restrict__ batch_id,
    _Float16* __restrict__ outh) {
    int i = blockIdx.x * 256 + threadIdx.x;
    if (i >= NN * (CC / 4)) return;
    int row = i >> 5;
    int q = i & 31;
    int b = batch_id[row];
    float4 v  = ((const float4*)in)[i];
    float4 sc = ((const float4*)ss)[q];
    float4 sh = ((const float4*)(ss + CC))[q];
    float4 s  = ((const float4*)(se + (size_t)b * CC))[q];
    Half4 o;
    o.x = (_Float16)(fmaxf(fmaf(v.x, sc.x, sh.x), 0.f) * s.x);
    o.y = (_Float16)(fmaxf(fmaf(v.y, sc.y, sh.y), 0.f) * s.y);
    o.z = (_Float16)(fmaxf(fmaf(v.z, sc.z, sh.z), 0.f) * s.z);
    o.w = (_Float16)(fmaxf(fmaf(v.w, sc.w, sh.w), 0.f) * s.w);
    ((Half4*)outh)[i] = o;
}

__global__ __launch_bounds__(256) void final_kernel(
    float* __restrict__ out, const float* __restrict__ ss,
    const float* __restrict__ x) {
    int i = blockIdx.x * 256 + threadIdx.x;
    if (i >= NN * (CC / 4)) return;
    int q = i & 31;
    float4 v  = ((float4*)out)[i];
    float4 r  = ((const float4*)x)[i];
    float4 sc = ((const float4*)ss)[q];
    float4 sh = ((const float4*)(ss + CC))[q];
    float4 o;
    o.x = fmaxf(fmaf(v.x, sc.x, sh.x) + r.x, 0.f);
    o.y = fmaxf(fmaf(v.y, sc.y, sh.y) + r.y, 0.f);
    o.z = fmaxf(fmaf(v.z, sc.z, sh.z) + r.z, 0.f);
    o.w = fmaxf(fmaf(v.w, sc.w, sh.w) + r.w, 0.f);
    ((float4*)out)[i] = o;
}

extern "C" void kernel_launch(void* const* d_in, const int* in_sizes, int n_in,
                              void* d_out, int out_size, void* d_ws, size_t ws_size,
                              hipStream_t stream) {
    const float* x        = (const float*)d_in[0];
    const int*   batch_id = (const int*)d_in[1];
    const int*   in_idx   = (const int*)d_in[2];
    const int*   out_idx  = (const int*)d_in[3];
    const float* W1       = (const float*)d_in[4];
    const float* W2       = (const float*)d_in[5];
    const float* fc1      = (const float*)d_in[6];
    const float* fc2      = (const float*)d_in[7];
    const float* gamma1   = (const float*)d_in[8];
    const float* beta1    = (const float*)d_in[9];
    const float* gamma2   = (const float*)d_in[10];
    const float* beta2    = (const float*)d_in[11];
    float* out = (float*)d_out;

    char* ws = (char*)d_ws;
    size_t off = 0;
    auto alloc = [&](size_t bytes) {
        void* p = ws + off;
        off = (off + bytes + 255) & ~(size_t)255;
        return p;
    };
    // shared buffers (both paths)
    _Float16* xh     = (_Float16*)alloc((size_t)NN * CC * 2);
    _Float16* w1t    = (_Float16*)alloc((size_t)KK * CC * CC * 2);
    _Float16* w2t    = (_Float16*)alloc((size_t)KK * CC * CC * 2);
    float*    out1   = (float*)alloc((size_t)NN * CC * 4);
    float*    stats1 = (float*)alloc(2 * CC * 4);
    float*    ss1    = (float*)alloc(2 * CC * 4);
    float*    stats2 = (float*)alloc(2 * CC * 4);
    float*    ss2    = (float*)alloc(2 * CC * 4);
    float*    pooled = (float*)alloc(BBATCH * CC * 4);
    float*    sebuf  = (float*)alloc(BBATCH * CC * 4);
    // CSR + y buffers (fast path only)
    int*      counts  = (int*)alloc((size_t)NN * 4);
    int*      offsets = (int*)alloc((size_t)(NN + 1) * 4);
    int*      bsum    = (int*)alloc(NSB * 4);
    int*      bbase   = (int*)alloc(NSB * 4);
    int*      rank    = (int*)alloc((size_t)NPAIR * 4);
    _Float16* ybuf    = (_Float16*)alloc((size_t)NPAIR * CC * 2);
    bool fast = (off <= ws_size);

    _Float16* out1h = xh;   // xh dead after conv1's gemm

    int elem4 = NN * (CC / 4);
    int g_e4 = (elem4 + 255) / 256;
    int g_pair = (NPAIR + 255) / 256;
    int rpb = (NN + 2047) / 2048;   // 49

    convert_x_kernel<<<g_e4, 256, 0, stream>>>(x, xh);
    transpose_w_kernel<<<KK * 16, 256, 0, stream>>>(W1, w1t);
    transpose_w_kernel<<<KK * 16, 256, 0, stream>>>(W2, w2t);

    hipMemsetAsync(stats1, 0, 2 * CC * 4, stream);
    hipMemsetAsync(stats2, 0, 2 * CC * 4, stream);
    hipMemsetAsync(pooled, 0, BBATCH * CC * 4, stream);

    if (fast) {
        // CSR build (shared by both convs)
        hipMemsetAsync(counts, 0, (size_t)NN * 4, stream);
        hist_kernel<<<g_pair, 256, 0, stream>>>(out_idx, counts);
        scan1_kernel<<<NSB, 256, 0, stream>>>(counts, offsets, bsum);
        scan2_kernel<<<1, 128, 0, stream>>>(bsum, bbase);
        scan3_kernel<<<NSB, 256, 0, stream>>>(offsets, bbase);
        fill_kernel<<<g_pair, 256, 0, stream>>>(out_idx, offsets, counts, rank);

        ygemm_kernel<<<KK * NBLK, 256, 0, stream>>>(xh, w1t, in_idx, rank, ybuf);
        reduce_kernel<<<NN / 16, 256, 0, stream>>>(ybuf, offsets, out1);
    } else {
        hipMemsetAsync(out1, 0, (size_t)NN * CC * 4, stream);
        conv_kernel<<<KK * NBLK, 256, 0, stream>>>(xh, w1t, in_idx, out_idx, out1);
    }

    bn_stats_kernel<<<2048, 256, 0, stream>>>(out1, stats1, NN, rpb);
    bn_finalize_kernel<<<1, 128, 0, stream>>>(stats1, gamma1, beta1, ss1);
    pool_kernel<<<2048, 256, 0, stream>>>(out1, ss1, batch_id, pooled, NN, rpb);
    se_kernel<<<1, 256, 0, stream>>>(pooled, fc1, fc2, sebuf);
    scale_convert_kernel<<<g_e4, 256, 0, stream>>>(out1, ss1, sebuf, batch_id, out1h);

    if (fast) {
        ygemm_kernel<<<KK * NBLK, 256, 0, stream>>>(out1h, w2t, in_idx, rank, ybuf);
        reduce_kernel<<<NN / 16, 256, 0, stream>>>(ybuf, offsets, out);
    } else {
        hipMemsetAsync(out, 0, (size_t)NN * CC * 4, stream);
        conv_kernel<<<KK * NBLK, 256, 0, stream>>>(out1h, w2t, in_idx, out_idx, out);
    }

    bn_stats_kernel<<<2048, 256, 0, stream>>>(out, stats2, NN, rpb);
    bn_finalize_kernel<<<1, 128, 0, stream>>>(stats2, gamma2, beta2, ss2);
    final_kernel<<<g_e4, 256, 0, stream>>>(out, ss2, x);
}

// Round 5
// 914.918 us; speedup vs baseline: 1.7996x; 1.7996x over previous
//
#include <hip/hip_runtime.h>

#define NN 100000
#define CC 128
#define KK 27
#define MM 60000
#define NPAIR (KK * MM)            // 1,620,000
#define BBATCH 8
#define CRR 32
#define TM 64
#define NBLK ((MM + TM - 1) / TM)  // 938
#define NSB 98                     // ceil(NN / 1024)

typedef _Float16 half8 __attribute__((ext_vector_type(8)));
typedef float floatx4 __attribute__((ext_vector_type(4)));

struct __align__(8) Half4 { _Float16 x, y, z, w; };

// slot->channel permutation: slot p holds channel c = ((p&7)<<4)|(p>>3).
// This is the MFMA-natural layout: lane lr's half8 (slots lr*8..lr*8+7) holds
// channels {i*16+lr}. Inverse: slot(c) = ((c&15)<<3)|(c>>4).
__device__ __forceinline__ int cperm(int p) { return ((p & 7) << 4) | (p >> 3); }

// ---------------- conversions ----------------

__global__ __launch_bounds__(256) void convert_x_kernel(
    const float* __restrict__ x, _Float16* __restrict__ xh) {
    int i = blockIdx.x * 256 + threadIdx.x;
    if (i >= NN * (CC / 4)) return;
    float4 v = ((const float4*)x)[i];
    Half4 o;
    o.x = (_Float16)v.x; o.y = (_Float16)v.y;
    o.z = (_Float16)v.z; o.w = (_Float16)v.w;
    ((Half4*)xh)[i] = o;
}

// Wt[k][co][slot] = W[k][ci][co] with slot = ci (perm=0) or slot=perm^-1(ci) (perm=1)
__global__ __launch_bounds__(256) void transpose_w_kernel(
    const float* __restrict__ W, _Float16* __restrict__ Wt, int perm) {
    __shared__ float tile[32][33];
    int k = blockIdx.x >> 4;
    int tl = blockIdx.x & 15;
    int tr = (tl >> 2) * 32;       // ci base
    int tc = (tl & 3) * 32;        // co base
    int c = threadIdx.x & 31;
    int r8 = threadIdx.x >> 5;
    const float* Wk = W + (size_t)k * CC * CC;
    _Float16* Wo = Wt + (size_t)k * CC * CC;
    #pragma unroll
    for (int i = 0; i < 4; ++i) {
        int r = r8 + i * 8;
        tile[r][c] = Wk[(tr + r) * CC + tc + c];
    }
    __syncthreads();
    #pragma unroll
    for (int i = 0; i < 4; ++i) {
        int r = r8 + i * 8;
        int ci = tr + c;
        int col = perm ? (((ci & 15) << 3) | (ci >> 4)) : ci;
        Wo[(tc + r) * CC + col] = (_Float16)tile[c][r];
    }
}

// ---------------- per-group CSR build ----------------

__global__ __launch_bounds__(256) void hist_kernel(
    const int* __restrict__ oidx, int* __restrict__ counts, int GS) {
    int i = blockIdx.x * 256 + threadIdx.x;
    if (i < NPAIR) {
        int k = i / MM;
        int g = k / GS;
        atomicAdd(&counts[(size_t)g * NN + oidx[i]], 1);
    }
}

__global__ __launch_bounds__(256) void scan1_kernel(
    const int* __restrict__ counts, int* __restrict__ offsets, int* __restrict__ bsum) {
    __shared__ int ls[256];
    int g = blockIdx.y;
    const int* cg = counts + (size_t)g * NN;
    int* og = offsets + (size_t)g * (NN + 1);
    int b = blockIdx.x, t = threadIdx.x;
    int base = b * 1024 + t * 4;
    int v0 = (base + 0 < NN) ? cg[base + 0] : 0;
    int v1 = (base + 1 < NN) ? cg[base + 1] : 0;
    int v2 = (base + 2 < NN) ? cg[base + 2] : 0;
    int v3 = (base + 3 < NN) ? cg[base + 3] : 0;
    int s = v0 + v1 + v2 + v3;
    ls[t] = s;
    __syncthreads();
    for (int off = 1; off < 256; off <<= 1) {
        int x = (t >= off) ? ls[t - off] : 0;
        __syncthreads();
        if (t >= off) ls[t] += x;
        __syncthreads();
    }
    int ep = ls[t] - s;
    if (base + 0 < NN) og[base + 0] = ep;
    if (base + 1 < NN) og[base + 1] = ep + v0;
    if (base + 2 < NN) og[base + 2] = ep + v0 + v1;
    if (base + 3 < NN) og[base + 3] = ep + v0 + v1 + v2;
    if (t == 255) bsum[g * NSB + b] = ls[255];
}

__global__ void scan2_kernel(const int* __restrict__ bsum, int* __restrict__ bbase) {
    __shared__ int ls[128];
    int g = blockIdx.y;
    int t = threadIdx.x;
    int s = (t < NSB) ? bsum[g * NSB + t] : 0;
    ls[t] = s;
    __syncthreads();
    for (int off = 1; off < 128; off <<= 1) {
        int x = (t >= off) ? ls[t - off] : 0;
        __syncthreads();
        if (t >= off) ls[t] += x;
        __syncthreads();
    }
    if (t < NSB) bbase[g * NSB + t] = ls[t] - s;
}

__global__ __launch_bounds__(256) void scan3_kernel(
    int* __restrict__ offsets, const int* __restrict__ bbase, int GS) {
    int g = blockIdx.y;
    int* og = offsets + (size_t)g * (NN + 1);
    int b = blockIdx.x, t = threadIdx.x;
    int add = bbase[g * NSB + b];
    int base = b * 1024 + t * 4;
    #pragma unroll
    for (int i = 0; i < 4; ++i)
        if (base + i < NN) og[base + i] += add;
    if (b == 0 && t == 0) {
        int k0 = g * GS, k1 = min(KK, k0 + GS);
        og[NN] = (k1 - k0) * MM;
    }
}

__global__ __launch_bounds__(256) void fill_kernel(
    const int* __restrict__ oidx, const int* __restrict__ offsets,
    int* __restrict__ counts, int* __restrict__ rank, int GS) {
    int i = blockIdx.x * 256 + threadIdx.x;
    if (i < NPAIR) {
        int k = i / MM;
        int g = k / GS;
        int o = oidx[i];
        int old = atomicSub(&counts[(size_t)g * NN + o], 1);
        rank[i] = offsets[(size_t)g * (NN + 1) + o] + old - 1;
    }
}

// ---------------- conv phase 1: gather-MFMA -> y (group-CSR-ordered rows) ----
// A fragments gathered directly global->VGPR (no LDS staging). B staged in LDS.
__global__ __launch_bounds__(256) void ygemm_kernel(
    const _Float16* __restrict__ xh,     // [NN][CC] (slot space must match Wt ci space)
    const _Float16* __restrict__ Wt,     // [KK][co][slot]
    const int* __restrict__ in_idx,      // [KK][MM]
    const int* __restrict__ rank,        // [NPAIR] (within-group CSR position)
    _Float16* __restrict__ y,            // [<=GS*MM][CC] slot-space rows
    int k0)
{
    __shared__ __align__(16) _Float16 Blds[CC][136];
    int k  = k0 + blockIdx.x / NBLK;
    int tb = blockIdx.x % NBLK;
    int m0 = tb * TM;
    int tid = threadIdx.x;

    const _Float16* Wk = Wt + (size_t)k * CC * CC;
    #pragma unroll
    for (int i = 0; i < 8; ++i) {
        int ch = tid + i * 256;
        int r = ch >> 4;
        int c8 = (ch & 15) << 3;
        *(half8*)&Blds[r][c8] = *(const half8*)&Wk[r * CC + c8];
    }

    int w = tid >> 6, lane = tid & 63;
    int lr = lane & 15, lk = lane >> 4;

    // direct A gather: lane (lr,lk) needs row m0+w*16+lr, cols [kc*32+lk*8, +8)
    int mr = m0 + w * 16 + lr;
    int mrc = min(mr, MM - 1);                  // tail clamp; result unused if OOB
    int g = in_idx[(size_t)k * MM + mrc];
    const _Float16* arow = &xh[(size_t)g * CC + lk * 8];
    half8 a0 = *(const half8*)(arow);
    half8 a1 = *(const half8*)(arow + 32);
    half8 a2 = *(const half8*)(arow + 64);
    half8 a3 = *(const half8*)(arow + 96);

    __syncthreads();

    floatx4 acc[8];
    #pragma unroll
    for (int f = 0; f < 8; ++f) acc[f] = (floatx4){0.f, 0.f, 0.f, 0.f};

    #pragma unroll
    for (int f = 0; f < 8; ++f)
        acc[f] = __builtin_amdgcn_mfma_f32_16x16x32_f16(a0, *(const half8*)&Blds[f * 16 + lr][0 * 32 + lk * 8], acc[f], 0, 0, 0);
    #pragma unroll
    for (int f = 0; f < 8; ++f)
        acc[f] = __builtin_amdgcn_mfma_f32_16x16x32_f16(a1, *(const half8*)&Blds[f * 16 + lr][1 * 32 + lk * 8], acc[f], 0, 0, 0);
    #pragma unroll
    for (int f = 0; f < 8; ++f)
        acc[f] = __builtin_amdgcn_mfma_f32_16x16x32_f16(a2, *(const half8*)&Blds[f * 16 + lr][2 * 32 + lk * 8], acc[f], 0, 0, 0);
    #pragma unroll
    for (int f = 0; f < 8; ++f)
        acc[f] = __builtin_amdgcn_mfma_f32_16x16x32_f16(a3, *(const half8*)&Blds[f * 16 + lr][3 * 32 + lk * 8], acc[f], 0, 0, 0);

    // store: D row (pair m) = m0 + w*16 + lk*4 + j, channel = f*16+lr -> slot lr*8+f
    const int* rk = rank + (size_t)k * MM;
    int rbase = w * 16 + lk * 4;
    #pragma unroll
    for (int j = 0; j < 4; ++j) {
        int m = m0 + rbase + j;
        if (m < MM) {
            int pos = rk[m];
            half8 hv;
            #pragma unroll
            for (int f = 0; f < 8; ++f) hv[f] = (_Float16)acc[f][j];
            *(half8*)&y[(size_t)pos * CC + lr * 8] = hv;
        }
    }
}

// ---------------- conv phase 2: contiguous segment reduce ----------------
// MODE: 0 = f16 store (slot space), 1 = f16 accumulate (slot space)
template<int MODE>
__global__ __launch_bounds__(256) void reduce_kernel(
    const _Float16* __restrict__ y, const int* __restrict__ offs,
    _Float16* __restrict__ outh) {
    int t = threadIdx.x;
    int o = blockIdx.x * 16 + (t >> 4);
    int l = t & 15;
    int s0 = offs[o], s1 = offs[o + 1];
    if (MODE == 1 && s0 == s1) return;   // nothing to add
    float a[8] = {0.f, 0.f, 0.f, 0.f, 0.f, 0.f, 0.f, 0.f};
    for (int p = s0; p < s1; ++p) {
        half8 v = *(const half8*)&y[(size_t)p * CC + l * 8];
        #pragma unroll
        for (int i = 0; i < 8; ++i) a[i] += (float)v[i];
    }
    _Float16* op = outh + (size_t)o * CC + l * 8;
    if (MODE == 1) {
        half8 old = *(half8*)op;
        #pragma unroll
        for (int i = 0; i < 8; ++i) a[i] += (float)old[i];
    }
    half8 hv;
    #pragma unroll
    for (int i = 0; i < 8; ++i) hv[i] = (_Float16)a[i];
    *(half8*)op = hv;
}

// ---------------- BN stats ----------------

__global__ __launch_bounds__(256) void bn_stats_f16_kernel(
    const _Float16* __restrict__ in, float* __restrict__ stats, int rpb) {
    int p = threadIdx.x & 127;
    int h = threadIdx.x >> 7;
    int r0 = blockIdx.x * rpb;
    int r1 = min(NN, r0 + rpb);
    float s = 0.f, s2 = 0.f;
    for (int r = r0 + h; r < r1; r += 2) {
        float v = (float)in[(size_t)r * CC + p];
        s += v; s2 += v * v;
    }
    __shared__ float ls[256], ls2[256];
    ls[threadIdx.x] = s; ls2[threadIdx.x] = s2;
    __syncthreads();
    if (h == 0) {
        atomicAdd(&stats[p],      ls[p] + ls[p + 128]);
        atomicAdd(&stats[CC + p], ls2[p] + ls2[p + 128]);
    }
}

__global__ __launch_bounds__(256) void bn_stats_f32_kernel(
    const float* __restrict__ in, float* __restrict__ stats, int rpb) {
    int p = threadIdx.x & 127;
    int h = threadIdx.x >> 7;
    int r0 = blockIdx.x * rpb;
    int r1 = min(NN, r0 + rpb);
    float s = 0.f, s2 = 0.f;
    for (int r = r0 + h; r < r1; r += 2) {
        float v = in[(size_t)r * CC + p];
        s += v; s2 += v * v;
    }
    __shared__ float ls[256], ls2[256];
    ls[threadIdx.x] = s; ls2[threadIdx.x] = s2;
    __syncthreads();
    if (h == 0) {
        atomicAdd(&stats[p],      ls[p] + ls[p + 128]);
        atomicAdd(&stats[CC + p], ls2[p] + ls2[p + 128]);
    }
}

// stats indexed by slot p; gamma/beta indexed by channel. perm=1: slot space.
__global__ void bn_finalize_kernel(
    const float* __restrict__ stats, const float* __restrict__ gamma,
    const float* __restrict__ beta, float* __restrict__ ss, int perm) {
    int p = threadIdx.x;
    if (p < CC) {
        int c = perm ? cperm(p) : p;
        float mean = stats[p] * (1.f / NN);
        float var = stats[CC + p] * (1.f / NN) - mean * mean;
        float sc = gamma[c] * rsqrtf(var + 1e-5f);
        ss[p] = sc;
        ss[CC + p] = beta[c] - mean * sc;
    }
}

// ---------------- fused BN+ReLU -> segment pool (slot space) ----------------
__global__ __launch_bounds__(256) void pool_kernel(
    const _Float16* __restrict__ in, const float* __restrict__ ss,
    const int* __restrict__ batch_id, float* __restrict__ pooled, int rpb) {
    int p = threadIdx.x & 127;
    int h = threadIdx.x >> 7;
    float sc = ss[p], sh = ss[CC + p];
    int r0 = blockIdx.x * rpb;
    int r1 = min(NN, r0 + rpb);
    float acc = 0.f; int cur = -1;
    for (int r = r0 + h; r < r1; r += 2) {
        int b = batch_id[r];
        float v = fmaxf(fmaf((float)in[(size_t)r * CC + p], sc, sh), 0.f);
        if (b != cur) {
            if (cur >= 0) atomicAdd(&pooled[cur * CC + p], acc);
            cur = b; acc = 0.f;
        }
        acc += v;
    }
    if (cur >= 0) atomicAdd(&pooled[cur * CC + p], acc);
}

// ---------------- SE MLP (slot space in/out) ----------------
__global__ __launch_bounds__(256) void se_kernel(
    const float* __restrict__ pooled, const float* __restrict__ fc1,
    const float* __restrict__ fc2, float* __restrict__ se) {
    __shared__ float h[BBATCH][CRR];
    int tid = threadIdx.x;
    {
        int b = tid >> 5, j = tid & 31;
        float a = 0.f;
        for (int p = 0; p < CC; ++p) a += pooled[b * CC + p] * fc1[cperm(p) * CRR + j];
        h[b][j] = fmaxf(a, 0.f);
    }
    __syncthreads();
    #pragma unroll
    for (int i = 0; i < 4; ++i) {
        int idx = tid + i * 256;
        int b = idx >> 7, p = idx & 127;
        int c = cperm(p);
        float a = 0.f;
        #pragma unroll
        for (int j = 0; j < CRR; ++j) a += h[b][j] * fc2[j * CC + c];
        se[b * CC + p] = 1.f / (1.f + expf(-a));
    }
}

// ---------------- fused BN+ReLU+SE-scale (f16 slot -> f16 slot) ----------------
__global__ __launch_bounds__(256) void scale_convert_kernel(
    const _Float16* __restrict__ oh, const float* __restrict__ ss,
    const float* __restrict__ se, const int* __restrict__ batch_id,
    _Float16* __restrict__ xo) {
    int idx = blockIdx.x * 256 + threadIdx.x;      // over NN*16
    if (idx >= NN * 16) return;
    int row = idx >> 4;
    int l = idx & 15;
    int b = batch_id[row];
    half8 v = *(const half8*)(oh + (size_t)row * CC + l * 8);
    half8 o;
    #pragma unroll
    for (int i = 0; i < 8; ++i) {
        int p = l * 8 + i;
        float t = fmaxf(fmaf((float)v[i], ss[p], ss[CC + p]), 0.f) * se[b * CC + p];
        o[i] = (_Float16)t;
    }
    *(half8*)(xo + (size_t)row * CC + l * 8) = o;
}

// ---------------- fused BN2 + residual + ReLU: f16 slot -> f32 channel ----------
__global__ __launch_bounds__(256) void final2_kernel(
    const _Float16* __restrict__ oh, const float* __restrict__ ss,
    const float* __restrict__ x, float* __restrict__ dout) {
    int idx = blockIdx.x * 256 + threadIdx.x;      // over NN*16
    if (idx >= NN * 16) return;
    int row = idx >> 4;
    int l = idx & 15;
    half8 v = *(const half8*)(oh + (size_t)row * CC + l * 8);
    #pragma unroll
    for (int i = 0; i < 8; ++i) {
        int p = l * 8 + i;
        int c = (i << 4) | l;                      // cperm(p)
        float r = x[(size_t)row * CC + c];
        dout[(size_t)row * CC + c] = fmaxf(fmaf((float)v[i], ss[p], ss[CC + p]) + r, 0.f);
    }
}

// ---------------- fallback path (atomic scatter, validated round 2) ----------
__global__ __launch_bounds__(256) void conv_kernel(
    const _Float16* __restrict__ xh, const _Float16* __restrict__ Wt,
    const int* __restrict__ in_idx, const int* __restrict__ out_idx,
    float* __restrict__ out) {
    __shared__ __align__(16) _Float16 Alds[TM][136];
    __shared__ __align__(16) _Float16 Blds[CC][136];
    int k  = blockIdx.x / NBLK;
    int tb = blockIdx.x % NBLK;
    int m0 = tb * TM;
    int tid = threadIdx.x;
    const _Float16* Wk = Wt + (size_t)k * CC * CC;
    #pragma unroll
    for (int i = 0; i < 8; ++i) {
        int ch = tid + i * 256;
        int r = ch >> 4, c8 = (ch & 15) << 3;
        *(half8*)&Blds[r][c8] = *(const half8*)&Wk[r * CC + c8];
    }
    const int* ii = in_idx + (size_t)k * MM + m0;
    #pragma unroll
    for (int i = 0; i < 4; ++i) {
        int r = (tid >> 4) + i * 16, c8 = (tid & 15) << 3;
        if (m0 + r < MM) {
            int g = ii[r];
            *(half8*)&Alds[r][c8] = *(const half8*)&xh[(size_t)g * CC + c8];
        } else { half8 z = {}; *(half8*)&Alds[r][c8] = z; }
    }
    __syncthreads();
    int w = tid >> 6, lane = tid & 63;
    int lr = lane & 15, lk = lane >> 4;
    floatx4 acc[8];
    #pragma unroll
    for (int f = 0; f < 8; ++f) acc[f] = (floatx4){0.f, 0.f, 0.f, 0.f};
    #pragma unroll
    for (int kc = 0; kc < 4; ++kc) {
        half8 a = *(const half8*)&Alds[w * 16 + lr][kc * 32 + lk * 8];
        #pragma unroll
        for (int f = 0; f < 8; ++f) {
            half8 bb = *(const half8*)&Blds[f * 16 + lr][kc * 32 + lk * 8];
            acc[f] = __builtin_amdgcn_mfma_f32_16x16x32_f16(a, bb, acc[f], 0, 0, 0);
        }
    }
    const int* oi = out_idx + (size_t)k * MM + m0;
    int mb = w * 16 + lk * 4;
    #pragma unroll
    for (int j = 0; j < 4; ++j) {
        int m = m0 + mb + j;
        if (m < MM) {
            int o = oi[mb + j];
            float* orow = out + (size_t)o * CC + lr;
            #pragma unroll
            for (int f = 0; f < 8; ++f)
                atomicAdd(orow + f * 16, acc[f][j]);
        }
    }
}

// fallback: f32 channel-space -> f16 slot-space
__global__ __launch_bounds__(256) void c2p_kernel(
    const float* __restrict__ in, _Float16* __restrict__ outh) {
    int i = blockIdx.x * 256 + threadIdx.x;
    if (i >= NN * CC) return;
    int row = i >> 7, p = i & 127;
    outh[i] = (_Float16)in[(size_t)row * CC + cperm(p)];
}

// fallback final: f32 channel-space in-place + residual
__global__ __launch_bounds__(256) void final_kernel(
    float* __restrict__ out, const float* __restrict__ ss,
    const float* __restrict__ x) {
    int i = blockIdx.x * 256 + threadIdx.x;
    if (i >= NN * (CC / 4)) return;
    int q = i & 31;
    float4 v  = ((float4*)out)[i];
    float4 r  = ((const float4*)x)[i];
    float4 sc = ((const float4*)ss)[q];
    float4 sh = ((const float4*)(ss + CC))[q];
    float4 o;
    o.x = fmaxf(fmaf(v.x, sc.x, sh.x) + r.x, 0.f);
    o.y = fmaxf(fmaf(v.y, sc.y, sh.y) + r.y, 0.f);
    o.z = fmaxf(fmaf(v.z, sc.z, sh.z) + r.z, 0.f);
    o.w = fmaxf(fmaf(v.w, sc.w, sh.w) + r.w, 0.f);
    ((float4*)out)[i] = o;
}

extern "C" void kernel_launch(void* const* d_in, const int* in_sizes, int n_in,
                              void* d_out, int out_size, void* d_ws, size_t ws_size,
                              hipStream_t stream) {
    const float* x        = (const float*)d_in[0];
    const int*   batch_id = (const int*)d_in[1];
    const int*   in_idx   = (const int*)d_in[2];
    const int*   out_idx  = (const int*)d_in[3];
    const float* W1       = (const float*)d_in[4];
    const float* W2       = (const float*)d_in[5];
    const float* fc1      = (const float*)d_in[6];
    const float* fc2      = (const float*)d_in[7];
    const float* gamma1   = (const float*)d_in[8];
    const float* beta1    = (const float*)d_in[9];
    const float* gamma2   = (const float*)d_in[10];
    const float* beta2    = (const float*)d_in[11];
    float* out = (float*)d_out;

    char* ws = (char*)d_ws;
    auto al = [](size_t v) { return (v + 255) & ~(size_t)255; };

    // fixed region
    size_t o_xh = 0;
    size_t o_w1 = al(o_xh + (size_t)NN * CC * 2);
    size_t o_w2 = al(o_w1 + (size_t)KK * CC * CC * 2);
    size_t o_oh = al(o_w2 + (size_t)KK * CC * CC * 2);
    size_t o_sm = al(o_oh + (size_t)NN * CC * 2);
    size_t fixed_end = al(o_sm + 6 * 4096);

    // choose P: smallest group count whose layout fits ws
    static const int PL[10] = {1, 2, 3, 4, 5, 6, 7, 9, 14, 27};
    int P = -1, GS = 0;
    size_t o_cnt = 0, o_off = 0, o_bs = 0, o_bb = 0, o_rank = 0, o_y = 0;
    for (int t = 0; t < 10; ++t) {
        int p = PL[t];
        int gs = (KK + p - 1) / p;
        size_t a = fixed_end;
        size_t c0 = a; a = al(a + (size_t)p * NN * 4);
        size_t c1 = a; a = al(a + (size_t)p * (NN + 1) * 4);
        size_t c2 = a; a = al(a + (size_t)p * NSB * 4);
        size_t c3 = a; a = al(a + (size_t)p * NSB * 4);
        size_t c4 = a; a = al(a + (size_t)NPAIR * 4);
        size_t c5 = a; a = al(a + (size_t)gs * MM * CC * 2);
        if (a <= ws_size) {
            P = p; GS = gs;
            o_cnt = c0; o_off = c1; o_bs = c2; o_bb = c3; o_rank = c4; o_y = c5;
            break;
        }
    }

    _Float16* xh  = (_Float16*)(ws + o_xh);
    _Float16* w1t = (_Float16*)(ws + o_w1);
    _Float16* w2t = (_Float16*)(ws + o_w2);
    _Float16* oh  = (_Float16*)(ws + o_oh);   // conv1 out (slot f16); reused for conv2 out
    float* stats1 = (float*)(ws + o_sm);
    float* ss1    = stats1 + 256;
    float* stats2 = ss1 + 256;
    float* ss2    = stats2 + 256;
    float* pooled = ss2 + 256;
    float* sebuf  = pooled + BBATCH * CC;

    int g_e4 = (NN * (CC / 4) + 255) / 256;   // 12500
    int g_16 = (NN * 16 + 255) / 256;         // 6250
    int g_pair = (NPAIR + 255) / 256;         // 6329
    int rpb = (NN + 2047) / 2048;             // 49

    convert_x_kernel<<<g_e4, 256, 0, stream>>>(x, xh);
    transpose_w_kernel<<<KK * 16, 256, 0, stream>>>(W1, w1t, 0);
    transpose_w_kernel<<<KK * 16, 256, 0, stream>>>(W2, w2t, 1);

    hipMemsetAsync(stats1, 0, 2 * CC * 4, stream);
    hipMemsetAsync(stats2, 0, 2 * CC * 4, stream);
    hipMemsetAsync(pooled, 0, BBATCH * CC * 4, stream);

    if (P > 0) {
        int* counts  = (int*)(ws + o_cnt);
        int* offsets = (int*)(ws + o_off);
        int* bsum    = (int*)(ws + o_bs);
        int* bbase   = (int*)(ws + o_bb);
        int* rank    = (int*)(ws + o_rank);
        _Float16* ybuf = (_Float16*)(ws + o_y);

        // per-group CSR build (shared by both convs)
        hipMemsetAsync(counts, 0, (size_t)P * NN * 4, stream);
        hist_kernel<<<g_pair, 256, 0, stream>>>(out_idx, counts, GS);
        scan1_kernel<<<dim3(NSB, P), 256, 0, stream>>>(counts, offsets, bsum);
        scan2_kernel<<<dim3(1, P), 128, 0, stream>>>(bsum, bbase);
        scan3_kernel<<<dim3(NSB, P), 256, 0, stream>>>(offsets, bbase, GS);
        fill_kernel<<<g_pair, 256, 0, stream>>>(out_idx, offsets, counts, rank, GS);

        // conv1
        for (int g = 0; g < P; ++g) {
            int k0 = g * GS, k1 = min(KK, k0 + GS), kn = k1 - k0;
            if (kn <= 0) break;
            ygemm_kernel<<<kn * NBLK, 256, 0, stream>>>(xh, w1t, in_idx, rank, ybuf, k0);
            const int* offG = offsets + (size_t)g * (NN + 1);
            if (g == 0) reduce_kernel<0><<<NN / 16, 256, 0, stream>>>(ybuf, offG, oh);
            else        reduce_kernel<1><<<NN / 16, 256, 0, stream>>>(ybuf, offG, oh);
        }

        bn_stats_f16_kernel<<<2048, 256, 0, stream>>>(oh, stats1, rpb);
        bn_finalize_kernel<<<1, 128, 0, stream>>>(stats1, gamma1, beta1, ss1, 1);
        pool_kernel<<<2048, 256, 0, stream>>>(oh, ss1, batch_id, pooled, rpb);
        se_kernel<<<1, 256, 0, stream>>>(pooled, fc1, fc2, sebuf);
        scale_convert_kernel<<<g_16, 256, 0, stream>>>(oh, ss1, sebuf, batch_id, xh);

        // conv2 (oh is dead -> reuse as conv2 accumulator)
        for (int g = 0; g < P; ++g) {
            int k0 = g * GS, k1 = min(KK, k0 + GS), kn = k1 - k0;
            if (kn <= 0) break;
            ygemm_kernel<<<kn * NBLK, 256, 0, stream>>>(xh, w2t, in_idx, rank, ybuf, k0);
            const int* offG = offsets + (size_t)g * (NN + 1);
            if (g == 0) reduce_kernel<0><<<NN / 16, 256, 0, stream>>>(ybuf, offG, oh);
            else        reduce_kernel<1><<<NN / 16, 256, 0, stream>>>(ybuf, offG, oh);
        }

        bn_stats_f16_kernel<<<2048, 256, 0, stream>>>(oh, stats2, rpb);
        bn_finalize_kernel<<<1, 128, 0, stream>>>(stats2, gamma2, beta2, ss2, 1);
        final2_kernel<<<g_16, 256, 0, stream>>>(oh, ss2, x, out);
    } else {
        // fallback: atomic scatter using d_out as f32 scratch
        hipMemsetAsync(out, 0, (size_t)NN * CC * 4, stream);
        conv_kernel<<<KK * NBLK, 256, 0, stream>>>(xh, w1t, in_idx, out_idx, out);
        c2p_kernel<<<(NN * CC + 255) / 256, 256, 0, stream>>>(out, oh);

        bn_stats_f16_kernel<<<2048, 256, 0, stream>>>(oh, stats1, rpb);
        bn_finalize_kernel<<<1, 128, 0, stream>>>(stats1, gamma1, beta1, ss1, 1);
        pool_kernel<<<2048, 256, 0, stream>>>(oh, ss1, batch_id, pooled, rpb);
        se_kernel<<<1, 256, 0, stream>>>(pooled, fc1, fc2, sebuf);
        scale_convert_kernel<<<g_16, 256, 0, stream>>>(oh, ss1, sebuf, batch_id, xh);

        hipMemsetAsync(out, 0, (size_t)NN * CC * 4, stream);
        conv_kernel<<<KK * NBLK, 256, 0, stream>>>(xh, w2t, in_idx, out_idx, out);

        bn_stats_f32_kernel<<<2048, 256, 0, stream>>>(out, stats2, rpb);
        bn_finalize_kernel<<<1, 128, 0, stream>>>(stats2, gamma2, beta2, ss2, 0);
        final_kernel<<<g_e4, 256, 0, stream>>>(out, ss2, x);
    }
}

// Round 9
// 889.272 us; speedup vs baseline: 1.8515x; 1.0288x over previous
//
#include <hip/hip_runtime.h>

#define NN 100000
#define CC 128
#define KK 27
#define MM 60000
#define NPAIR (KK * MM)            // 1,620,000
#define BBATCH 8
#define CRR 32
#define TM 64
#define NBLK ((MM + TM - 1) / TM)  // 938
#define NSB 98                     // ceil(NN / 1024)

typedef _Float16 half8 __attribute__((ext_vector_type(8)));
typedef float floatx4 __attribute__((ext_vector_type(4)));

struct __align__(8) Half4 { _Float16 x, y, z, w; };

// slot->channel permutation: slot p holds channel c = ((p&7)<<4)|(p>>3).
__device__ __forceinline__ int cperm(int p) { return ((p & 7) << 4) | (p >> 3); }

// ---------------- conversions ----------------

__global__ __launch_bounds__(256) void convert_x_kernel(
    const float* __restrict__ x, _Float16* __restrict__ xh) {
    int i = blockIdx.x * 256 + threadIdx.x;
    if (i >= NN * (CC / 4)) return;
    float4 v = ((const float4*)x)[i];
    Half4 o;
    o.x = (_Float16)v.x; o.y = (_Float16)v.y;
    o.z = (_Float16)v.z; o.w = (_Float16)v.w;
    ((Half4*)xh)[i] = o;
}

// Wt[k][co][slot] = W[k][ci][co] with slot = ci (perm=0) or slot=perm^-1(ci) (perm=1)
__global__ __launch_bounds__(256) void transpose_w_kernel(
    const float* __restrict__ W, _Float16* __restrict__ Wt, int perm) {
    __shared__ float tile[32][33];
    int k = blockIdx.x >> 4;
    int tl = blockIdx.x & 15;
    int tr = (tl >> 2) * 32;       // ci base
    int tc = (tl & 3) * 32;        // co base
    int c = threadIdx.x & 31;
    int r8 = threadIdx.x >> 5;
    const float* Wk = W + (size_t)k * CC * CC;
    _Float16* Wo = Wt + (size_t)k * CC * CC;
    #pragma unroll
    for (int i = 0; i < 4; ++i) {
        int r = r8 + i * 8;
        tile[r][c] = Wk[(tr + r) * CC + tc + c];
    }
    __syncthreads();
    #pragma unroll
    for (int i = 0; i < 4; ++i) {
        int r = r8 + i * 8;
        int ci = tr + c;
        int col = perm ? (((ci & 15) << 3) | (ci >> 4)) : ci;
        Wo[(tc + r) * CC + col] = (_Float16)tile[c][r];
    }
}

// ---------------- per-group CSR build (rank-free) ----------------
// hist also emits seq[i] = within-(group,node) arrival index; ygemm later
// computes the CSR position as offsets[g][o] + seq[i] -> no fill pass.

__global__ __launch_bounds__(256) void hist_kernel(
    const int* __restrict__ oidx, int* __restrict__ counts,
    int* __restrict__ seq, int GS) {
    int i = blockIdx.x * 256 + threadIdx.x;
    if (i < NPAIR) {
        int k = i / MM;
        int g = k / GS;
        seq[i] = atomicAdd(&counts[(size_t)g * NN + oidx[i]], 1);
    }
}

__global__ __launch_bounds__(256) void scan1_kernel(
    const int* __restrict__ counts, int* __restrict__ offsets, int* __restrict__ bsum) {
    __shared__ int ls[256];
    int g = blockIdx.y;
    const int* cg = counts + (size_t)g * NN;
    int* og = offsets + (size_t)g * (NN + 1);
    int b = blockIdx.x, t = threadIdx.x;
    int base = b * 1024 + t * 4;
    int v0 = (base + 0 < NN) ? cg[base + 0] : 0;
    int v1 = (base + 1 < NN) ? cg[base + 1] : 0;
    int v2 = (base + 2 < NN) ? cg[base + 2] : 0;
    int v3 = (base + 3 < NN) ? cg[base + 3] : 0;
    int s = v0 + v1 + v2 + v3;
    ls[t] = s;
    __syncthreads();
    for (int off = 1; off < 256; off <<= 1) {
        int x = (t >= off) ? ls[t - off] : 0;
        __syncthreads();
        if (t >= off) ls[t] += x;
        __syncthreads();
    }
    int ep = ls[t] - s;
    if (base + 0 < NN) og[base + 0] = ep;
    if (base + 1 < NN) og[base + 1] = ep + v0;
    if (base + 2 < NN) og[base + 2] = ep + v0 + v1;
    if (base + 3 < NN) og[base + 3] = ep + v0 + v1 + v2;
    if (t == 255) bsum[g * NSB + b] = ls[255];
}

__global__ void scan2_kernel(const int* __restrict__ bsum, int* __restrict__ bbase) {
    __shared__ int ls[128];
    int g = blockIdx.y;
    int t = threadIdx.x;
    int s = (t < NSB) ? bsum[g * NSB + t] : 0;
    ls[t] = s;
    __syncthreads();
    for (int off = 1; off < 128; off <<= 1) {
        int x = (t >= off) ? ls[t - off] : 0;
        __syncthreads();
        if (t >= off) ls[t] += x;
        __syncthreads();
    }
    if (t < NSB) bbase[g * NSB + t] = ls[t] - s;
}

__global__ __launch_bounds__(256) void scan3_kernel(
    int* __restrict__ offsets, const int* __restrict__ bbase, int GS) {
    int g = blockIdx.y;
    int* og = offsets + (size_t)g * (NN + 1);
    int b = blockIdx.x, t = threadIdx.x;
    int add = bbase[g * NSB + b];
    int base = b * 1024 + t * 4;
    #pragma unroll
    for (int i = 0; i < 4; ++i)
        if (base + i < NN) og[base + i] += add;
    if (b == 0 && t == 0) {
        int k0 = g * GS, k1 = min(KK, k0 + GS);
        og[NN] = (k1 - k0) * MM;
    }
}

// ---------------- conv phase 1: gather-MFMA -> y (group-CSR-ordered rows) ----
__global__ __launch_bounds__(256) void ygemm_kernel(
    const _Float16* __restrict__ xh,     // [NN][CC] slot space
    const _Float16* __restrict__ Wt,     // [KK][co][slot]
    const int* __restrict__ in_idx,      // [KK][MM]
    const int* __restrict__ out_idx,     // [KK][MM]
    const int* __restrict__ seq,         // [NPAIR]
    const int* __restrict__ offG,        // [NN+1] this group's CSR offsets
    _Float16* __restrict__ y,            // [<=GS*MM][CC]
    int k0)
{
    __shared__ __align__(16) _Float16 Blds[CC][136];
    int k  = k0 + blockIdx.x / NBLK;
    int tb = blockIdx.x % NBLK;
    int m0 = tb * TM;
    int tid = threadIdx.x;

    const _Float16* Wk = Wt + (size_t)k * CC * CC;
    #pragma unroll
    for (int i = 0; i < 8; ++i) {
        int ch = tid + i * 256;
        int r = ch >> 4;
        int c8 = (ch & 15) << 3;
        *(half8*)&Blds[r][c8] = *(const half8*)&Wk[r * CC + c8];
    }

    int w = tid >> 6, lane = tid & 63;
    int lr = lane & 15, lk = lane >> 4;

    // direct A gather: lane (lr,lk) reads row m0+w*16+lr, cols [kc*32+lk*8, +8)
    int mr = m0 + w * 16 + lr;
    int mrc = min(mr, MM - 1);
    int g = in_idx[(size_t)k * MM + mrc];
    const _Float16* arow = &xh[(size_t)g * CC + lk * 8];
    half8 a0 = *(const half8*)(arow);
    half8 a1 = *(const half8*)(arow + 32);
    half8 a2 = *(const half8*)(arow + 64);
    half8 a3 = *(const half8*)(arow + 96);

    __syncthreads();

    floatx4 acc[8];
    #pragma unroll
    for (int f = 0; f < 8; ++f) acc[f] = (floatx4){0.f, 0.f, 0.f, 0.f};

    #pragma unroll
    for (int f = 0; f < 8; ++f)
        acc[f] = __builtin_amdgcn_mfma_f32_16x16x32_f16(a0, *(const half8*)&Blds[f * 16 + lr][0 * 32 + lk * 8], acc[f], 0, 0, 0);
    #pragma unroll
    for (int f = 0; f < 8; ++f)
        acc[f] = __builtin_amdgcn_mfma_f32_16x16x32_f16(a1, *(const half8*)&Blds[f * 16 + lr][1 * 32 + lk * 8], acc[f], 0, 0, 0);
    #pragma unroll
    for (int f = 0; f < 8; ++f)
        acc[f] = __builtin_amdgcn_mfma_f32_16x16x32_f16(a2, *(const half8*)&Blds[f * 16 + lr][2 * 32 + lk * 8], acc[f], 0, 0, 0);
    #pragma unroll
    for (int f = 0; f < 8; ++f)
        acc[f] = __builtin_amdgcn_mfma_f32_16x16x32_f16(a3, *(const half8*)&Blds[f * 16 + lr][3 * 32 + lk * 8], acc[f], 0, 0, 0);

    // store: pair m = m0 + w*16 + lk*4 + j; pos = offG[out_idx[m]] + seq[m]
    const int* oi = out_idx + (size_t)k * MM;
    const int* sq = seq + (size_t)k * MM;
    int rbase = w * 16 + lk * 4;
    #pragma unroll
    for (int j = 0; j < 4; ++j) {
        int m = m0 + rbase + j;
        if (m < MM) {
            int pos = offG[oi[m]] + sq[m];
            half8 hv;
            #pragma unroll
            for (int f = 0; f < 8; ++f) hv[f] = (_Float16)acc[f][j];
            *(half8*)&y[(size_t)pos * CC + lr * 8] = hv;
        }
    }
}

// ---------------- conv phase 2: contiguous segment reduce ----------------
// MODE: 0 = f16 store (slot space), 1 = f16 accumulate (slot space)
template<int MODE>
__global__ __launch_bounds__(256) void reduce_kernel(
    const _Float16* __restrict__ y, const int* __restrict__ offs,
    _Float16* __restrict__ outh) {
    int t = threadIdx.x;
    int o = blockIdx.x * 16 + (t >> 4);
    int l = t & 15;
    int s0 = offs[o], s1 = offs[o + 1];
    if (MODE == 1 && s0 == s1) return;
    float a[8] = {0.f, 0.f, 0.f, 0.f, 0.f, 0.f, 0.f, 0.f};
    for (int p = s0; p < s1; ++p) {
        half8 v = *(const half8*)&y[(size_t)p * CC + l * 8];
        #pragma unroll
        for (int i = 0; i < 8; ++i) a[i] += (float)v[i];
    }
    _Float16* op = outh + (size_t)o * CC + l * 8;
    if (MODE == 1) {
        half8 old = *(half8*)op;
        #pragma unroll
        for (int i = 0; i < 8; ++i) a[i] += (float)old[i];
    }
    half8 hv;
    #pragma unroll
    for (int i = 0; i < 8; ++i) hv[i] = (_Float16)a[i];
    *(half8*)op = hv;
}

// ---------------- BN stats ----------------

__global__ __launch_bounds__(256) void bn_stats_f16_kernel(
    const _Float16* __restrict__ in, float* __restrict__ stats, int rpb) {
    int p = threadIdx.x & 127;
    int h = threadIdx.x >> 7;
    int r0 = blockIdx.x * rpb;
    int r1 = min(NN, r0 + rpb);
    float s = 0.f, s2 = 0.f;
    for (int r = r0 + h; r < r1; r += 2) {
        float v = (float)in[(size_t)r * CC + p];
        s += v; s2 += v * v;
    }
    __shared__ float ls[256], ls2[256];
    ls[threadIdx.x] = s; ls2[threadIdx.x] = s2;
    __syncthreads();
    if (h == 0) {
        atomicAdd(&stats[p],      ls[p] + ls[p + 128]);
        atomicAdd(&stats[CC + p], ls2[p] + ls2[p + 128]);
    }
}

__global__ __launch_bounds__(256) void bn_stats_f32_kernel(
    const float* __restrict__ in, float* __restrict__ stats, int rpb) {
    int p = threadIdx.x & 127;
    int h = threadIdx.x >> 7;
    int r0 = blockIdx.x * rpb;
    int r1 = min(NN, r0 + rpb);
    float s = 0.f, s2 = 0.f;
    for (int r = r0 + h; r < r1; r += 2) {
        float v = in[(size_t)r * CC + p];
        s += v; s2 += v * v;
    }
    __shared__ float ls[256], ls2[256];
    ls[threadIdx.x] = s; ls2[threadIdx.x] = s2;
    __syncthreads();
    if (h == 0) {
        atomicAdd(&stats[p],      ls[p] + ls[p + 128]);
        atomicAdd(&stats[CC + p], ls2[p] + ls2[p + 128]);
    }
}

// stats indexed by slot p; gamma/beta indexed by channel. perm=1: slot space.
__global__ void bn_finalize_kernel(
    const float* __restrict__ stats, const float* __restrict__ gamma,
    const float* __restrict__ beta, float* __restrict__ ss, int perm) {
    int p = threadIdx.x;
    if (p < CC) {
        int c = perm ? cperm(p) : p;
        float mean = stats[p] * (1.f / NN);
        float var = stats[CC + p] * (1.f / NN) - mean * mean;
        float sc = gamma[c] * rsqrtf(var + 1e-5f);
        ss[p] = sc;
        ss[CC + p] = beta[c] - mean * sc;
    }
}

// ---------------- fused BN+ReLU -> segment pool (slot space) ----------------
__global__ __launch_bounds__(256) void pool_kernel(
    const _Float16* __restrict__ in, const float* __restrict__ ss,
    const int* __restrict__ batch_id, float* __restrict__ pooled, int rpb) {
    int p = threadIdx.x & 127;
    int h = threadIdx.x >> 7;
    float sc = ss[p], sh = ss[CC + p];
    int r0 = blockIdx.x * rpb;
    int r1 = min(NN, r0 + rpb);
    float acc = 0.f; int cur = -1;
    for (int r = r0 + h; r < r1; r += 2) {
        int b = batch_id[r];
        float v = fmaxf(fmaf((float)in[(size_t)r * CC + p], sc, sh), 0.f);
        if (b != cur) {
            if (cur >= 0) atomicAdd(&pooled[cur * CC + p], acc);
            cur = b; acc = 0.f;
        }
        acc += v;
    }
    if (cur >= 0) atomicAdd(&pooled[cur * CC + p], acc);
}

// ---------------- SE MLP (slot space in/out) ----------------
__global__ __launch_bounds__(256) void se_kernel(
    const float* __restrict__ pooled, const float* __restrict__ fc1,
    const float* __restrict__ fc2, float* __restrict__ se) {
    __shared__ float h[BBATCH][CRR];
    int tid = threadIdx.x;
    {
        int b = tid >> 5, j = tid & 31;
        float a = 0.f;
        for (int p = 0; p < CC; ++p) a += pooled[b * CC + p] * fc1[cperm(p) * CRR + j];
        h[b][j] = fmaxf(a, 0.f);
    }
    __syncthreads();
    #pragma unroll
    for (int i = 0; i < 4; ++i) {
        int idx = tid + i * 256;
        int b = idx >> 7, p = idx & 127;
        int c = cperm(p);
        float a = 0.f;
        #pragma unroll
        for (int j = 0; j < CRR; ++j) a += h[b][j] * fc2[j * CC + c];
        se[b * CC + p] = 1.f / (1.f + expf(-a));
    }
}

// ---------------- fused BN+ReLU+SE-scale (f16 slot -> f16 slot) ----------------
__global__ __launch_bounds__(256) void scale_convert_kernel(
    const _Float16* __restrict__ oh, const float* __restrict__ ss,
    const float* __restrict__ se, const int* __restrict__ batch_id,
    _Float16* __restrict__ xo) {
    int idx = blockIdx.x * 256 + threadIdx.x;      // over NN*16
    if (idx >= NN * 16) return;
    int row = idx >> 4;
    int l = idx & 15;
    int b = batch_id[row];
    half8 v = *(const half8*)(oh + (size_t)row * CC + l * 8);
    half8 o;
    #pragma unroll
    for (int i = 0; i < 8; ++i) {
        int p = l * 8 + i;
        float t = fmaxf(fmaf((float)v[i], ss[p], ss[CC + p]), 0.f) * se[b * CC + p];
        o[i] = (_Float16)t;
    }
    *(half8*)(xo + (size_t)row * CC + l * 8) = o;
}

// ---------------- fused BN2 + residual + ReLU: f16 slot -> f32 channel ----------
__global__ __launch_bounds__(256) void final2_kernel(
    const _Float16* __restrict__ oh, const float* __restrict__ ss,
    const float* __restrict__ x, float* __restrict__ dout) {
    int idx = blockIdx.x * 256 + threadIdx.x;      // over NN*16
    if (idx >= NN * 16) return;
    int row = idx >> 4;
    int l = idx & 15;
    half8 v = *(const half8*)(oh + (size_t)row * CC + l * 8);
    #pragma unroll
    for (int i = 0; i < 8; ++i) {
        int p = l * 8 + i;
        int c = (i << 4) | l;                      // cperm(p)
        float r = x[(size_t)row * CC + c];
        dout[(size_t)row * CC + c] = fmaxf(fmaf((float)v[i], ss[p], ss[CC + p]) + r, 0.f);
    }
}

// ---------------- fallback path (atomic scatter, validated round 2) ----------
__global__ __launch_bounds__(256) void conv_kernel(
    const _Float16* __restrict__ xh, const _Float16* __restrict__ Wt,
    const int* __restrict__ in_idx, const int* __restrict__ out_idx,
    float* __restrict__ out) {
    __shared__ __align__(16) _Float16 Alds[TM][136];
    __shared__ __align__(16) _Float16 Blds[CC][136];
    int k  = blockIdx.x / NBLK;
    int tb = blockIdx.x % NBLK;
    int m0 = tb * TM;
    int tid = threadIdx.x;
    const _Float16* Wk = Wt + (size_t)k * CC * CC;
    #pragma unroll
    for (int i = 0; i < 8; ++i) {
        int ch = tid + i * 256;
        int r = ch >> 4, c8 = (ch & 15) << 3;
        *(half8*)&Blds[r][c8] = *(const half8*)&Wk[r * CC + c8];
    }
    const int* ii = in_idx + (size_t)k * MM + m0;
    #pragma unroll
    for (int i = 0; i < 4; ++i) {
        int r = (tid >> 4) + i * 16, c8 = (tid & 15) << 3;
        if (m0 + r < MM) {
            int g = ii[r];
            *(half8*)&Alds[r][c8] = *(const half8*)&xh[(size_t)g * CC + c8];
        } else { half8 z = {}; *(half8*)&Alds[r][c8] = z; }
    }
    __syncthreads();
    int w = tid >> 6, lane = tid & 63;
    int lr = lane & 15, lk = lane >> 4;
    floatx4 acc[8];
    #pragma unroll
    for (int f = 0; f < 8; ++f) acc[f] = (floatx4){0.f, 0.f, 0.f, 0.f};
    #pragma unroll
    for (int kc = 0; kc < 4; ++kc) {
        half8 a = *(const half8*)&Alds[w * 16 + lr][kc * 32 + lk * 8];
        #pragma unroll
        for (int f = 0; f < 8; ++f) {
            half8 bb = *(const half8*)&Blds[f * 16 + lr][kc * 32 + lk * 8];
            acc[f] = __builtin_amdgcn_mfma_f32_16x16x32_f16(a, bb, acc[f], 0, 0, 0);
        }
    }
    const int* oi = out_idx + (size_t)k * MM + m0;
    int mb = w * 16 + lk * 4;
    #pragma unroll
    for (int j = 0; j < 4; ++j) {
        int m = m0 + mb + j;
        if (m < MM) {
            int o = oi[mb + j];
            float* orow = out + (size_t)o * CC + lr;
            #pragma unroll
            for (int f = 0; f < 8; ++f)
                atomicAdd(orow + f * 16, acc[f][j]);
        }
    }
}

// fallback: f32 channel-space -> f16 slot-space
__global__ __launch_bounds__(256) void c2p_kernel(
    const float* __restrict__ in, _Float16* __restrict__ outh) {
    int i = blockIdx.x * 256 + threadIdx.x;
    if (i >= NN * CC) return;
    int row = i >> 7, p = i & 127;
    outh[i] = (_Float16)in[(size_t)row * CC + cperm(p)];
}

// fallback final: f32 channel-space in-place + residual
__global__ __launch_bounds__(256) void final_kernel(
    float* __restrict__ out, const float* __restrict__ ss,
    const float* __restrict__ x) {
    int i = blockIdx.x * 256 + threadIdx.x;
    if (i >= NN * (CC / 4)) return;
    int q = i & 31;
    float4 v  = ((float4*)out)[i];
    float4 r  = ((const float4*)x)[i];
    float4 sc = ((const float4*)ss)[q];
    float4 sh = ((const float4*)(ss + CC))[q];
    float4 o;
    o.x = fmaxf(fmaf(v.x, sc.x, sh.x) + r.x, 0.f);
    o.y = fmaxf(fmaf(v.y, sc.y, sh.y) + r.y, 0.f);
    o.z = fmaxf(fmaf(v.z, sc.z, sh.z) + r.z, 0.f);
    o.w = fmaxf(fmaf(v.w, sc.w, sh.w) + r.w, 0.f);
    ((float4*)out)[i] = o;
}

extern "C" void kernel_launch(void* const* d_in, const int* in_sizes, int n_in,
                              void* d_out, int out_size, void* d_ws, size_t ws_size,
                              hipStream_t stream) {
    const float* x        = (const float*)d_in[0];
    const int*   batch_id = (const int*)d_in[1];
    const int*   in_idx   = (const int*)d_in[2];
    const int*   out_idx  = (const int*)d_in[3];
    const float* W1       = (const float*)d_in[4];
    const float* W2       = (const float*)d_in[5];
    const float* fc1      = (const float*)d_in[6];
    const float* fc2      = (const float*)d_in[7];
    const float* gamma1   = (const float*)d_in[8];
    const float* beta1    = (const float*)d_in[9];
    const float* gamma2   = (const float*)d_in[10];
    const float* beta2    = (const float*)d_in[11];
    float* out = (float*)d_out;

    char* ws = (char*)d_ws;
    auto al = [](size_t v) { return (v + 255) & ~(size_t)255; };

    // fixed region (~53 MB)
    size_t o_xh = 0;
    size_t o_w1 = al(o_xh + (size_t)NN * CC * 2);
    size_t o_w2 = al(o_w1 + (size_t)KK * CC * CC * 2);
    size_t o_oh = al(o_w2 + (size_t)KK * CC * CC * 2);
    size_t o_sm = al(o_oh + (size_t)NN * CC * 2);
    size_t fixed_end = al(o_sm + 6 * 4096);

    // P preference: 3 first (ybuf 138 MB -> LLC-resident, oh-RMW 2x/conv),
    // then growing P (smaller ybuf, more RMW); P=2,1 last (ybuf too big for LLC).
    static const int PL[10] = {3, 4, 5, 6, 7, 9, 14, 27, 2, 1};
    int P = -1, GS = 0;
    size_t o_cnt = 0, o_off = 0, o_bs = 0, o_bb = 0, o_seq = 0, o_y = 0;
    for (int t = 0; t < 10; ++t) {
        int p = PL[t];
        int gs = (KK + p - 1) / p;
        size_t a = fixed_end;
        size_t c0 = a; a = al(a + (size_t)p * NN * 4);
        size_t c1 = a; a = al(a + (size_t)p * (NN + 1) * 4);
        size_t c2 = a; a = al(a + (size_t)p * NSB * 4);
        size_t c3 = a; a = al(a + (size_t)p * NSB * 4);
        size_t c4 = a; a = al(a + (size_t)NPAIR * 4);
        size_t c5 = a; a = al(a + (size_t)gs * MM * CC * 2);
        if (a <= ws_size) {
            P = p; GS = gs;
            o_cnt = c0; o_off = c1; o_bs = c2; o_bb = c3; o_seq = c4; o_y = c5;
            break;
        }
    }

    _Float16* xh  = (_Float16*)(ws + o_xh);
    _Float16* w1t = (_Float16*)(ws + o_w1);
    _Float16* w2t = (_Float16*)(ws + o_w2);
    _Float16* oh  = (_Float16*)(ws + o_oh);   // conv out (slot f16); reused conv1->conv2
    float* stats1 = (float*)(ws + o_sm);
    float* ss1    = stats1 + 256;
    float* stats2 = ss1 + 256;
    float* ss2    = stats2 + 256;
    float* pooled = ss2 + 256;
    float* sebuf  = pooled + BBATCH * CC;

    int g_e4 = (NN * (CC / 4) + 255) / 256;   // 12500
    int g_16 = (NN * 16 + 255) / 256;         // 6250
    int g_pair = (NPAIR + 255) / 256;         // 6329
    int rpb = (NN + 2047) / 2048;             // 49

    convert_x_kernel<<<g_e4, 256, 0, stream>>>(x, xh);
    transpose_w_kernel<<<KK * 16, 256, 0, stream>>>(W1, w1t, 0);
    transpose_w_kernel<<<KK * 16, 256, 0, stream>>>(W2, w2t, 1);

    hipMemsetAsync(stats1, 0, 2 * CC * 4, stream);
    hipMemsetAsync(stats2, 0, 2 * CC * 4, stream);
    hipMemsetAsync(pooled, 0, BBATCH * CC * 4, stream);

    if (P > 0) {
        int* counts  = (int*)(ws + o_cnt);
        int* offsets = (int*)(ws + o_off);
        int* bsum    = (int*)(ws + o_bs);
        int* bbase   = (int*)(ws + o_bb);
        int* seq     = (int*)(ws + o_seq);
        _Float16* ybuf = (_Float16*)(ws + o_y);

        // per-group CSR build (shared by both convs); no fill pass
        hipMemsetAsync(counts, 0, (size_t)P * NN * 4, stream);
        hist_kernel<<<g_pair, 256, 0, stream>>>(out_idx, counts, seq, GS);
        scan1_kernel<<<dim3(NSB, P), 256, 0, stream>>>(counts, offsets, bsum);
        scan2_kernel<<<dim3(1, P), 128, 0, stream>>>(bsum, bbase);
        scan3_kernel<<<dim3(NSB, P), 256, 0, stream>>>(offsets, bbase, GS);

        // conv1
        for (int g = 0; g < P; ++g) {
            int k0 = g * GS, k1 = min(KK, k0 + GS), kn = k1 - k0;
            if (kn <= 0) break;
            const int* offG = offsets + (size_t)g * (NN + 1);
            ygemm_kernel<<<kn * NBLK, 256, 0, stream>>>(xh, w1t, in_idx, out_idx, seq, offG, ybuf, k0);
            if (g == 0) reduce_kernel<0><<<NN / 16, 256, 0, stream>>>(ybuf, offG, oh);
            else        reduce_kernel<1><<<NN / 16, 256, 0, stream>>>(ybuf, offG, oh);
        }

        bn_stats_f16_kernel<<<2048, 256, 0, stream>>>(oh, stats1, rpb);
        bn_finalize_kernel<<<1, 128, 0, stream>>>(stats1, gamma1, beta1, ss1, 1);
        pool_kernel<<<2048, 256, 0, stream>>>(oh, ss1, batch_id, pooled, rpb);
        se_kernel<<<1, 256, 0, stream>>>(pooled, fc1, fc2, sebuf);
        scale_convert_kernel<<<g_16, 256, 0, stream>>>(oh, ss1, sebuf, batch_id, xh);

        // conv2 (oh dead -> reuse as conv2 accumulator)
        for (int g = 0; g < P; ++g) {
            int k0 = g * GS, k1 = min(KK, k0 + GS), kn = k1 - k0;
            if (kn <= 0) break;
            const int* offG = offsets + (size_t)g * (NN + 1);
            ygemm_kernel<<<kn * NBLK, 256, 0, stream>>>(xh, w2t, in_idx, out_idx, seq, offG, ybuf, k0);
            if (g == 0) reduce_kernel<0><<<NN / 16, 256, 0, stream>>>(ybuf, offG, oh);
            else        reduce_kernel<1><<<NN / 16, 256, 0, stream>>>(ybuf, offG, oh);
        }

        bn_stats_f16_kernel<<<2048, 256, 0, stream>>>(oh, stats2, rpb);
        bn_finalize_kernel<<<1, 128, 0, stream>>>(stats2, gamma2, beta2, ss2, 1);
        final2_kernel<<<g_16, 256, 0, stream>>>(oh, ss2, x, out);
    } else {
        // fallback: atomic scatter using d_out as f32 scratch
        hipMemsetAsync(out, 0, (size_t)NN * CC * 4, stream);
        conv_kernel<<<KK * NBLK, 256, 0, stream>>>(xh, w1t, in_idx, out_idx, out);
        c2p_kernel<<<(NN * CC + 255) / 256, 256, 0, stream>>>(out, oh);

        bn_stats_f16_kernel<<<2048, 256, 0, stream>>>(oh, stats1, rpb);
        bn_finalize_kernel<<<1, 128, 0, stream>>>(stats1, gamma1, beta1, ss1, 1);
        pool_kernel<<<2048, 256, 0, stream>>>(oh, ss1, batch_id, pooled, rpb);
        se_kernel<<<1, 256, 0, stream>>>(pooled, fc1, fc2, sebuf);
        scale_convert_kernel<<<g_16, 256, 0, stream>>>(oh, ss1, sebuf, batch_id, xh);

        hipMemsetAsync(out, 0, (size_t)NN * CC * 4, stream);
        conv_kernel<<<KK * NBLK, 256, 0, stream>>>(xh, w2t, in_idx, out_idx, out);

        bn_stats_f32_kernel<<<2048, 256, 0, stream>>>(out, stats2, rpb);
        bn_finalize_kernel<<<1, 128, 0, stream>>>(stats2, gamma2, beta2, ss2, 0);
        final_kernel<<<g_e4, 256, 0, stream>>>(out, ss2, x);
    }
}